// Round 12
// baseline (150.682 us; speedup 1.0000x reference)
//
#include <hip/hip_runtime.h>

typedef short bf16x8 __attribute__((ext_vector_type(8)));
typedef float f32x4 __attribute__((ext_vector_type(4)));
typedef float f32x16 __attribute__((ext_vector_type(16)));
typedef unsigned short ushort_t;
typedef unsigned int uint32;

#define LAMBDA_INIT 0.7836057665316245f
#define TT 2048
#define EE 1024

__device__ __forceinline__ ushort_t f2bf(float x) {
  uint32 b = __float_as_uint(x);
  b += 0x7fffu + ((b >> 16) & 1u);   // round-to-nearest-even
  return (ushort_t)(b >> 16);
}

__device__ __forceinline__ uint32 cvtpk(float lo, float hi) {
  uint32 r;
  asm("v_cvt_pk_bf16_f32 %0, %1, %2" : "=v"(r) : "v"(lo), "v"(hi));
  return r;
}

// raw v_exp_f32 via hazard-safe builtin (args bounded; libm guard unnecessary)
__device__ __forceinline__ float fexp2(float x) {
#if __has_builtin(__builtin_amdgcn_exp2f)
  return __builtin_amdgcn_exp2f(x);
#else
  return exp2f(x);
#endif
}

__device__ __forceinline__ bf16x8 mkfrag(uint32 a, uint32 b, uint32 c, uint32 d) {
  union { uint32 w[4]; bf16x8 v; } u;
  u.w[0] = a; u.w[1] = b; u.w[2] = c; u.w[3] = d;
  return u.v;
}

__device__ __forceinline__ void gload16(const void* g, void* l) {
  __builtin_amdgcn_global_load_lds(
      (const __attribute__((address_space(1))) uint32*)g,
      (__attribute__((address_space(3))) uint32*)l, 16, 0, 0);
}

// ------------- fused fp32 -> bf16 conversion: X,Wq,Wk,Wv,Wo -> contiguous ws -------------
__global__ __launch_bounds__(256) void cvt_all(const float* __restrict__ X,
                                               const float* __restrict__ Wq,
                                               const float* __restrict__ Wk,
                                               const float* __restrict__ Wv,
                                               const float* __restrict__ Wo,
                                               ushort_t* __restrict__ out) {
  const int i = blockIdx.x * 256 + threadIdx.x;  // float4 index, 2097152 total
  const float* src;
  int off;
  if (i < 1048576)      { src = X;  off = 0; }
  else if (i < 1310720) { src = Wq; off = 1048576; }
  else if (i < 1572864) { src = Wk; off = 1310720; }
  else if (i < 1835008) { src = Wv; off = 1572864; }
  else                  { src = Wo; off = 1835008; }
  const float4 v = reinterpret_cast<const float4*>(src)[i - off];
  ushort4 o;
  o.x = f2bf(v.x); o.y = f2bf(v.y); o.z = f2bf(v.z); o.w = f2bf(v.w);
  reinterpret_cast<ushort4*>(out)[i] = o;
}

// ---------------- 128x128 bf16 GEMM (out-projection): C fp32 = A[M,K] @ B[N,K]^T ----------
__global__ __launch_bounds__(256) void gemm_bt(const ushort_t* __restrict__ A,
                                               const ushort_t* __restrict__ B,
                                               float* __restrict__ C,
                                               int M, int N, int K, float scale) {
  __shared__ ushort_t As[128 * 32];
  __shared__ ushort_t Bs[128 * 32];
  const int tid = threadIdx.x;
  const int lane = tid & 63, wid = tid >> 6;
  const int wr = wid >> 1, wc = wid & 1;
  const int r16 = lane & 15, g = lane >> 4;
  const int m0 = blockIdx.x * 128, n0 = blockIdx.y * 128;
  f32x4 acc[4][4] = {};
  for (int k0 = 0; k0 < K; k0 += 32) {
#pragma unroll
    for (int c = 0; c < 2; ++c) {
      int eo = wid * 1024 + c * 512 + lane * 8;
      int row = eo >> 5, col = eo & 31;
      gload16(A + (size_t)(m0 + row) * K + k0 + col, As + wid * 1024 + c * 512);
      gload16(B + (size_t)(n0 + row) * K + k0 + col, Bs + wid * 1024 + c * 512);
    }
    __syncthreads();
    bf16x8 af[4], bfg[4];
#pragma unroll
    for (int m = 0; m < 4; ++m)
      af[m] = *reinterpret_cast<const bf16x8*>(As + (wr * 64 + m * 16 + r16) * 32 + g * 8);
#pragma unroll
    for (int n = 0; n < 4; ++n)
      bfg[n] = *reinterpret_cast<const bf16x8*>(Bs + (wc * 64 + n * 16 + r16) * 32 + g * 8);
#pragma unroll
    for (int m = 0; m < 4; ++m)
#pragma unroll
      for (int n = 0; n < 4; ++n)
        acc[m][n] = __builtin_amdgcn_mfma_f32_16x16x32_bf16(af[m], bfg[n], acc[m][n], 0, 0, 0);
    __syncthreads();
  }
#pragma unroll
  for (int m = 0; m < 4; ++m)
#pragma unroll
    for (int n = 0; n < 4; ++n)
#pragma unroll
      for (int r = 0; r < 4; ++r) {
        int row = m0 + wr * 64 + m * 16 + g * 4 + r;
        int col = n0 + wc * 64 + n * 16 + r16;
        C[(size_t)row * N + col] = acc[m][n][r] * scale;
      }
}

// ---------------- 256x256 deep-pipelined QKV GEMM (T3+T4 structure) ----------------
#define SHALF(Sbase, Gbase)                                                  \
  do {                                                                       \
    _Pragma("unroll") for (int j_ = 0; j_ < 2; ++j_) {                       \
      const int c_ = wid * 2 + j_;                                           \
      gload16((Gbase) + (size_t)(c_ * 8 + (lane >> 3)) * EE +                \
                  (((lane & 7) ^ (lane >> 3)) << 3),                         \
              (Sbase) + c_ * 512);                                           \
    }                                                                        \
  } while (0)

#define CHUNK(mp)                                                            \
  do {                                                                       \
    __builtin_amdgcn_s_setprio(1);                                           \
    _Pragma("unroll") for (int mm_ = 0; mm_ < 2; ++mm_) {                    \
      const int m_ = (mp) * 2 + mm_;                                         \
      _Pragma("unroll") for (int n_ = 0; n_ < 4; ++n_) {                     \
        acc[m_][n_] = __builtin_amdgcn_mfma_f32_16x16x32_bf16(               \
            af[m_][0], bfr[n_][0], acc[m_][n_], 0, 0, 0);                    \
        acc[m_][n_] = __builtin_amdgcn_mfma_f32_16x16x32_bf16(               \
            af[m_][1], bfr[n_][1], acc[m_][n_], 0, 0, 0);                    \
      }                                                                      \
    }                                                                        \
    __builtin_amdgcn_s_setprio(0);                                           \
  } while (0)

__global__ __launch_bounds__(512, 2) void qkv_gemm256(const ushort_t* __restrict__ A,
                                                      const ushort_t* __restrict__ B,
                                                      ushort_t* __restrict__ C,
                                                      float scale) {
  __shared__ ushort_t Asm[2][16384];
  __shared__ ushort_t Bsm[2][16384];
  const int NKT = EE / 64;  // 16
  const int tid = threadIdx.x, lane = tid & 63, wid = tid >> 6;
  const int wr = wid >> 2, wc = wid & 3;
  const int r16 = lane & 15, g = lane >> 4;
  const int w = (blockIdx.x & 7) * 24 + (blockIdx.x >> 3);
  const int bx = w & 15, by = w >> 4;
  const int m0 = bx * 256, n0 = by * 256;
  const ushort_t* Ab = A + (size_t)m0 * EE;
  const ushort_t* Bb = B + (size_t)n0 * EE;

#pragma unroll
  for (int kt = 0; kt < 2; ++kt) {
    SHALF(Asm[kt], Ab + kt * 64);
    SHALF(Asm[kt] + 8192, Ab + (size_t)128 * EE + kt * 64);
    SHALF(Bsm[kt], Bb + kt * 64);
    SHALF(Bsm[kt] + 8192, Bb + (size_t)128 * EE + kt * 64);
  }

  f32x4 acc[8][4] = {};
  for (int t = 0; t < NKT; ++t) {
    const int b = t & 1;
    if (t < NKT - 1) asm volatile("s_waitcnt vmcnt(8)" ::: "memory");
    else             asm volatile("s_waitcnt vmcnt(0)" ::: "memory");
    __builtin_amdgcn_s_barrier();
    asm volatile("" ::: "memory");
    bf16x8 af[8][2], bfr[4][2];
#pragma unroll
    for (int m = 0; m < 8; ++m) {
      const int row = wr * 128 + m * 16 + r16;
#pragma unroll
      for (int kk = 0; kk < 2; ++kk)
        af[m][kk] = *reinterpret_cast<const bf16x8*>(
            Asm[b] + row * 64 + (((kk * 4 + g) ^ (r16 & 7)) << 3));
    }
#pragma unroll
    for (int n = 0; n < 4; ++n) {
      const int row = wc * 64 + n * 16 + r16;
#pragma unroll
      for (int kk = 0; kk < 2; ++kk)
        bfr[n][kk] = *reinterpret_cast<const bf16x8*>(
            Bsm[b] + row * 64 + (((kk * 4 + g) ^ (r16 & 7)) << 3));
    }
    asm volatile("s_waitcnt lgkmcnt(0)" ::: "memory");
    __builtin_amdgcn_s_barrier();
    asm volatile("" ::: "memory");
    const int ts = t + 2;
    const bool st = ts < NKT;
    if (st) SHALF(Asm[b], Ab + ts * 64);
    CHUNK(0);
    if (st) SHALF(Asm[b] + 8192, Ab + (size_t)128 * EE + ts * 64);
    CHUNK(1);
    if (st) SHALF(Bsm[b], Bb + ts * 64);
    CHUNK(2);
    if (st) SHALF(Bsm[b] + 8192, Bb + (size_t)128 * EE + ts * 64);
    CHUNK(3);
  }

  const size_t MN = (size_t)4096 * EE;
#pragma unroll
  for (int m = 0; m < 8; ++m)
#pragma unroll
    for (int n = 0; n < 4; ++n) {
      const int col = n0 + wc * 64 + n * 16 + r16;
      const int seg = col >> 10;
      const int cl = col & 1023;
      if (seg == 2) {
        int row0 = m0 + wr * 128 + m * 16 + g * 4;
        int bb2 = row0 >> 11, t0v = row0 & (TT - 1);
        ushort4 pk;
        pk.x = f2bf(acc[m][n][0]); pk.y = f2bf(acc[m][n][1]);
        pk.z = f2bf(acc[m][n][2]); pk.w = f2bf(acc[m][n][3]);
        *reinterpret_cast<ushort4*>(
            C + 2 * MN + ((size_t)(bb2 * 16 + (cl >> 6)) * 64 + (cl & 63)) * TT + t0v) = pk;
      } else {
        const float sc = (seg == 0) ? scale : 1.0f;
        const size_t base = (size_t)seg * MN;
#pragma unroll
        for (int r = 0; r < 4; ++r) {
          int row = m0 + wr * 128 + m * 16 + g * 4 + r;
          C[base + (size_t)row * EE + cl] = f2bf(acc[m][n][r] * sc);
        }
      }
    }
}

// ---------------- fused dual-softmax flash attention, intra-block kv-split ----------
// 8-wave blocks: waves 0-3 sweep kv[0:1024), waves 4-7 sweep kv[1024:2048) for
// the SAME 128 q-rows (wave w and w+4 share q0). No max tracking -> partials
// are exactly additive: merged post-loop via the dead staging LDS (2 phases).
// Doubles resident waves to 4/SIMD to fill barrier/latency idle.
// K/V per half: KVBLK=64, dbuf, 128B rows, (row&7) 16B-XOR swizzle (rule #21).

#define PHALF(sv, lacc, oT0, oT1, vf)                                                   \
  do {                                                                                  \
    float p_[16];                                                                       \
    _Pragma("unroll") for (int i_ = 0; i_ < 16; ++i_) p_[i_] = fexp2(sv[i_]);           \
    lacc += (((p_[0] + p_[1]) + (p_[2] + p_[3])) + ((p_[4] + p_[5]) + (p_[6] + p_[7]))) \
          + (((p_[8] + p_[9]) + (p_[10] + p_[11])) +                                    \
             ((p_[12] + p_[13]) + (p_[14] + p_[15])));                                  \
    auto wA_ = __builtin_amdgcn_permlane32_swap((int)cvtpk(p_[0], p_[1]),               \
                                                (int)cvtpk(p_[4], p_[5]), false, false);\
    auto wB_ = __builtin_amdgcn_permlane32_swap((int)cvtpk(p_[2], p_[3]),               \
                                                (int)cvtpk(p_[6], p_[7]), false, false);\
    auto wC_ = __builtin_amdgcn_permlane32_swap((int)cvtpk(p_[8], p_[9]),               \
                                                (int)cvtpk(p_[12], p_[13]), false, false);\
    auto wD_ = __builtin_amdgcn_permlane32_swap((int)cvtpk(p_[10], p_[11]),             \
                                                (int)cvtpk(p_[14], p_[15]), false, false);\
    bf16x8 pa0_ = mkfrag(wA_[0], wB_[0], wA_[1], wB_[1]);                               \
    bf16x8 pa1_ = mkfrag(wC_[0], wD_[0], wC_[1], wD_[1]);                               \
    oT0 = __builtin_amdgcn_mfma_f32_32x32x16_bf16(pa0_, vf[0][0], oT0, 0, 0, 0);        \
    oT0 = __builtin_amdgcn_mfma_f32_32x32x16_bf16(pa1_, vf[1][0], oT0, 0, 0, 0);        \
    oT1 = __builtin_amdgcn_mfma_f32_32x32x16_bf16(pa0_, vf[0][1], oT1, 0, 0, 0);        \
    oT1 = __builtin_amdgcn_mfma_f32_32x32x16_bf16(pa1_, vf[1][1], oT1, 0, 0, 0);        \
  } while (0)

// Stage one 64-kv tile for THIS wave's kv-half: 16 x 1KB chunks, 4 per wave
// (wsub 0..3), chunk c covers rows c*8..c*8+7.
#define STAGE(bi, kv0)                                                                  \
  do {                                                                                  \
    const int r8_ = lane >> 3;                                                          \
    const int g_ = (lane & 7) ^ r8_;                                                    \
    _Pragma("unroll") for (int c2_ = 0; c2_ < 2; ++c2_) {                               \
      const int c_ = wsub * 2 + c2_;                                                    \
      gload16(Kgh + (size_t)((kv0) + c_ * 8 + r8_) * EE + g_ * 8,                       \
              Ksp[bi] + c_ * 512);                                                      \
      gload16(Vgh + (size_t)(c_ * 8 + r8_) * TT + (kv0) + g_ * 8,                       \
              Vsp[bi] + c_ * 512);                                                      \
    }                                                                                   \
  } while (0)

__global__ __launch_bounds__(512, 2) void attn_fused(
    const ushort_t* __restrict__ Q, const ushort_t* __restrict__ K,
    const ushort_t* __restrict__ Vt,
    const float* __restrict__ lq1, const float* __restrict__ lk1,
    const float* __restrict__ lq2, const float* __restrict__ lk2,
    const float* __restrict__ w, ushort_t* __restrict__ X2) {
  // 64KB: K buffers [half][dbuf] 8KB each (32KB) + V buffers (32KB).
  // Reused post-loop as fp32 merge scratch.
  __shared__ ushort_t SMEM[32768];
  const int tid = threadIdx.x, lane = tid & 63, wid = tid >> 6;
  const int wsub = wid & 3, kvh = wid >> 2;
  const int l31 = lane & 31, hh = lane >> 5;
  // XCD swizzle: 16 q-blocks of one (b,h) slice land on one XCD
  const int bid = blockIdx.x;                    // 0..511
  const int slice = (bid & 7) + 8 * (bid >> 7);  // 0..31
  const int qb = (bid >> 3) & 15;                // 0..15
  const int bb = slice >> 4, h = slice & 15;
  const int q0 = qb * 128 + wsub * 32;

  // lambda scalar
  float prod = (lane < 32) ? lq1[l31] * lk1[l31] : lq2[l31] * lk2[l31];
#pragma unroll
  for (int off = 1; off < 32; off <<= 1) prod += __shfl_xor(prod, off, 32);
  const float lam = __expf(__shfl(prod, 0, 64)) - __expf(__shfl(prod, 32, 64)) + LAMBDA_INIT;

  // Q B-fragments (waves w and w+4 load the same q-rows)
  const ushort_t* Qp = Q + (size_t)(bb * TT + q0 + l31) * EE + h * 64 + hh * 8;
  const bf16x8 qf00 = *reinterpret_cast<const bf16x8*>(Qp);
  const bf16x8 qf01 = *reinterpret_cast<const bf16x8*>(Qp + 16);
  const bf16x8 qf10 = *reinterpret_cast<const bf16x8*>(Qp + 32);
  const bf16x8 qf11 = *reinterpret_cast<const bf16x8*>(Qp + 48);

  const ushort_t* Kgh = K + (size_t)bb * TT * EE + h * 64 + (size_t)(kvh * 1024) * EE;
  const ushort_t* Vgh = Vt + (size_t)(bb * 16 + h) * 64 * TT + kvh * 1024;
  ushort_t* const Ksp[2] = {SMEM + (kvh * 2) * 4096, SMEM + (kvh * 2 + 1) * 4096};
  ushort_t* const Vsp[2] = {SMEM + 16384 + (kvh * 2) * 4096,
                            SMEM + 16384 + (kvh * 2 + 1) * 4096};
  const int swz = (l31 & 7) << 3;

  f32x16 o00 = {}, o01 = {}, o10 = {}, o11 = {};
  float l0 = 0.f, l1 = 0.f;

  STAGE(0, 0);
  for (int it = 0; it < 16; ++it) {  // 16 x 64 kv per half
    const int cur = it & 1;
    __syncthreads();  // drains vmcnt: tile `it` staged (both halves); prior reads done
    if (it + 1 < 16) STAGE(cur ^ 1, (it + 1) * 64);

    const ushort_t* Kt_ = Ksp[cur];
    const ushort_t* Vt_ = Vsp[cur];
#pragma unroll
    for (int s = 0; s < 2; ++s) {  // kv sub-tiles 0-31 / 32-63
      bf16x8 kf[2][2], vf[2][2];
#pragma unroll
      for (int hf = 0; hf < 2; ++hf)
#pragma unroll
        for (int ks = 0; ks < 2; ++ks)
          kf[hf][ks] = *reinterpret_cast<const bf16x8*>(
              Kt_ + (s * 32 + l31) * 64 + ((hf * 32 + ks * 16 + hh * 8) ^ swz));
#pragma unroll
      for (int ks = 0; ks < 2; ++ks)
#pragma unroll
        for (int dc = 0; dc < 2; ++dc)
          vf[ks][dc] = *reinterpret_cast<const bf16x8*>(
              Vt_ + (dc * 32 + l31) * 64 + ((s * 32 + ks * 16 + hh * 8) ^ swz));

      __builtin_amdgcn_s_setprio(1);
      const f32x16 zz = {};
      f32x16 s0_ = __builtin_amdgcn_mfma_f32_32x32x16_bf16(kf[0][0], qf00, zz, 0, 0, 0);
      s0_ = __builtin_amdgcn_mfma_f32_32x32x16_bf16(kf[0][1], qf01, s0_, 0, 0, 0);
      f32x16 s1_ = __builtin_amdgcn_mfma_f32_32x32x16_bf16(kf[1][0], qf10, zz, 0, 0, 0);
      s1_ = __builtin_amdgcn_mfma_f32_32x32x16_bf16(kf[1][1], qf11, s1_, 0, 0, 0);
      __builtin_amdgcn_s_setprio(0);
      PHALF(s0_, l0, o00, o01, vf);
      PHALF(s1_, l1, o10, o11, vf);
    }
  }

  // ---- merge kv-halves through (now dead) staging LDS; exactly additive ----
  float* scr = (float*)SMEM;  // 16384 floats
  __syncthreads();            // all compute done; buffers reusable
  if (wid >= 4) {
    const int pw = wid - 4;
#pragma unroll
    for (int r = 0; r < 16; ++r) {
      scr[((pw * 2 + 0) * 16 + r) * 64 + lane] = o00[r];
      scr[((pw * 2 + 1) * 16 + r) * 64 + lane] = o01[r];
    }
    scr[8192 + pw * 64 + lane] = l0;
  }
  __syncthreads();
  if (wid < 4) {
#pragma unroll
    for (int r = 0; r < 16; ++r) {
      o00[r] += scr[((wid * 2 + 0) * 16 + r) * 64 + lane];
      o01[r] += scr[((wid * 2 + 1) * 16 + r) * 64 + lane];
    }
    l0 += scr[8192 + wid * 64 + lane];
  }
  __syncthreads();
  if (wid >= 4) {
    const int pw = wid - 4;
#pragma unroll
    for (int r = 0; r < 16; ++r) {
      scr[((pw * 2 + 0) * 16 + r) * 64 + lane] = o10[r];
      scr[((pw * 2 + 1) * 16 + r) * 64 + lane] = o11[r];
    }
    scr[8192 + pw * 64 + lane] = l1;
  }
  __syncthreads();
  if (wid < 4) {
#pragma unroll
    for (int r = 0; r < 16; ++r) {
      o10[r] += scr[((wid * 2 + 0) * 16 + r) * 64 + lane];
      o11[r] += scr[((wid * 2 + 1) * 16 + r) * 64 + lane];
    }
    l1 += scr[8192 + wid * 64 + lane];

    // l totals: lanes l31==q (lo and hi) hold disjoint kv partial sums
    auto t0 = __builtin_amdgcn_permlane32_swap(__float_as_int(l0), __float_as_int(l0),
                                               false, false);
    l0 = __int_as_float(t0[0]) + __int_as_float(t0[1]);
    auto t1 = __builtin_amdgcn_permlane32_swap(__float_as_int(l1), __float_as_int(l1),
                                               false, false);
    l1 = __int_as_float(t1[0]) + __int_as_float(t1[1]);

    const float w0v = w[l31];
    const float w1v = w[32 + l31];
#pragma unroll
    for (int r = 0; r < 16; ++r) {
      const int qrel = (r & 3) + 8 * (r >> 2) + 4 * hh;
      const float il0 = 1.0f / __shfl(l0, qrel, 64);
      const float il1 = lam / __shfl(l1, qrel, 64);
      const float x0 = o00[r] * il0 - o10[r] * il1;
      const float x1 = o01[r] * il0 - o11[r] * il1;
      float ss = x0 * x0 + x1 * x1;
#pragma unroll
      for (int off = 1; off < 32; off <<= 1) ss += __shfl_xor(ss, off, 64);
      const float sc = rsqrtf(ss * (1.0f / 64.0f) + 1e-5f) * (1.0f - LAMBDA_INIT);
      const size_t ob = (size_t)(bb * TT + q0 + qrel) * EE + h * 64 + l31;
      X2[ob] = f2bf(x0 * sc * w0v);
      X2[ob + 32] = f2bf(x1 * sc * w1v);
    }
  }
}

// ---------------- launch ----------------
extern "C" void kernel_launch(void* const* d_in, const int* in_sizes, int n_in,
                              void* d_out, int out_size, void* d_ws, size_t ws_size,
                              hipStream_t stream) {
  const float* X = (const float*)d_in[0];
  const float* Wq = (const float*)d_in[1];
  const float* Wk = (const float*)d_in[2];
  const float* Wv = (const float*)d_in[3];
  const float* Wo = (const float*)d_in[4];
  const float* lq1 = (const float*)d_in[5];
  const float* lk1 = (const float*)d_in[6];
  const float* lq2 = (const float*)d_in[7];
  const float* lk2 = (const float*)d_in[8];
  const float* slw = (const float*)d_in[9];

  const int M = 4096, E = EE;

  ushort_t* Xb = (ushort_t*)d_ws;            // M*E bf16
  ushort_t* Wqb = Xb + (size_t)M * E;        // E*E  (Wq,Wk,Wv,Wo contiguous)
  ushort_t* Wob = Wqb + (size_t)3 * E * E;
  ushort_t* Qb = Wob + (size_t)E * E;        // M*E  (Qb,Kb,Vtb contiguous)
  ushort_t* Kb = Qb + (size_t)M * E;
  ushort_t* Vtb = Kb + (size_t)M * E;
  ushort_t* X2 = Vtb + (size_t)M * E;

  cvt_all<<<8192, 256, 0, stream>>>(X, Wq, Wk, Wv, Wo, Xb);

  // fused QKV projection, 256^2 deep-pipelined. Q prescaled by hd^-0.5 * log2e.
  qkv_gemm256<<<192, 512, 0, stream>>>(Xb, Wqb, Qb,
                                       0.17677669529663687f * 1.4426950408889634f);

  attn_fused<<<512, 512, 0, stream>>>(Qb, Kb, Vtb, lq1, lk1, lq2, lk2, slw, X2);

  gemm_bt<<<dim3(M / 128, E / 128), 256, 0, stream>>>(X2, Wob, (float*)d_out, M, E, E,
                                                      1.0f);
}

// Round 13
// 136.774 us; speedup vs baseline: 1.1017x; 1.1017x over previous
//
#include <hip/hip_runtime.h>

typedef short bf16x8 __attribute__((ext_vector_type(8)));
typedef float f32x4 __attribute__((ext_vector_type(4)));
typedef float f32x16 __attribute__((ext_vector_type(16)));
typedef unsigned short ushort_t;
typedef unsigned int uint32;

#define LAMBDA_INIT 0.7836057665316245f
#define TT 2048
#define EE 1024

__device__ __forceinline__ ushort_t f2bf(float x) {
  uint32 b = __float_as_uint(x);
  b += 0x7fffu + ((b >> 16) & 1u);   // round-to-nearest-even
  return (ushort_t)(b >> 16);
}

__device__ __forceinline__ uint32 cvtpk(float lo, float hi) {
  uint32 r;
  asm("v_cvt_pk_bf16_f32 %0, %1, %2" : "=v"(r) : "v"(lo), "v"(hi));
  return r;
}

// raw v_exp_f32 via hazard-safe builtin (args bounded; libm guard unnecessary)
__device__ __forceinline__ float fexp2(float x) {
#if __has_builtin(__builtin_amdgcn_exp2f)
  return __builtin_amdgcn_exp2f(x);
#else
  return exp2f(x);
#endif
}

__device__ __forceinline__ bf16x8 mkfrag(uint32 a, uint32 b, uint32 c, uint32 d) {
  union { uint32 w[4]; bf16x8 v; } u;
  u.w[0] = a; u.w[1] = b; u.w[2] = c; u.w[3] = d;
  return u.v;
}

__device__ __forceinline__ void gload16(const void* g, void* l) {
  __builtin_amdgcn_global_load_lds(
      (const __attribute__((address_space(1))) uint32*)g,
      (__attribute__((address_space(3))) uint32*)l, 16, 0, 0);
}

// ------------- fused fp32 -> bf16 conversion: X,Wq,Wk,Wv,Wo -> contiguous ws -------------
__global__ __launch_bounds__(256) void cvt_all(const float* __restrict__ X,
                                               const float* __restrict__ Wq,
                                               const float* __restrict__ Wk,
                                               const float* __restrict__ Wv,
                                               const float* __restrict__ Wo,
                                               ushort_t* __restrict__ out) {
  const int i = blockIdx.x * 256 + threadIdx.x;  // float4 index, 2097152 total
  const float* src;
  int off;
  if (i < 1048576)      { src = X;  off = 0; }
  else if (i < 1310720) { src = Wq; off = 1048576; }
  else if (i < 1572864) { src = Wk; off = 1310720; }
  else if (i < 1835008) { src = Wv; off = 1572864; }
  else                  { src = Wo; off = 1835008; }
  const float4 v = reinterpret_cast<const float4*>(src)[i - off];
  ushort4 o;
  o.x = f2bf(v.x); o.y = f2bf(v.y); o.z = f2bf(v.z); o.w = f2bf(v.w);
  reinterpret_cast<ushort4*>(out)[i] = o;
}

// ---------------- 128x128 bf16 GEMM (out-projection): C fp32 = A[M,K] @ B[N,K]^T ----------
__global__ __launch_bounds__(256) void gemm_bt(const ushort_t* __restrict__ A,
                                               const ushort_t* __restrict__ B,
                                               float* __restrict__ C,
                                               int M, int N, int K, float scale) {
  __shared__ ushort_t As[128 * 32];
  __shared__ ushort_t Bs[128 * 32];
  const int tid = threadIdx.x;
  const int lane = tid & 63, wid = tid >> 6;
  const int wr = wid >> 1, wc = wid & 1;
  const int r16 = lane & 15, g = lane >> 4;
  const int m0 = blockIdx.x * 128, n0 = blockIdx.y * 128;
  f32x4 acc[4][4] = {};
  for (int k0 = 0; k0 < K; k0 += 32) {
#pragma unroll
    for (int c = 0; c < 2; ++c) {
      int eo = wid * 1024 + c * 512 + lane * 8;
      int row = eo >> 5, col = eo & 31;
      gload16(A + (size_t)(m0 + row) * K + k0 + col, As + wid * 1024 + c * 512);
      gload16(B + (size_t)(n0 + row) * K + k0 + col, Bs + wid * 1024 + c * 512);
    }
    __syncthreads();
    bf16x8 af[4], bfg[4];
#pragma unroll
    for (int m = 0; m < 4; ++m)
      af[m] = *reinterpret_cast<const bf16x8*>(As + (wr * 64 + m * 16 + r16) * 32 + g * 8);
#pragma unroll
    for (int n = 0; n < 4; ++n)
      bfg[n] = *reinterpret_cast<const bf16x8*>(Bs + (wc * 64 + n * 16 + r16) * 32 + g * 8);
#pragma unroll
    for (int m = 0; m < 4; ++m)
#pragma unroll
      for (int n = 0; n < 4; ++n)
        acc[m][n] = __builtin_amdgcn_mfma_f32_16x16x32_bf16(af[m], bfg[n], acc[m][n], 0, 0, 0);
    __syncthreads();
  }
#pragma unroll
  for (int m = 0; m < 4; ++m)
#pragma unroll
    for (int n = 0; n < 4; ++n)
#pragma unroll
      for (int r = 0; r < 4; ++r) {
        int row = m0 + wr * 64 + m * 16 + g * 4 + r;
        int col = n0 + wc * 64 + n * 16 + r16;
        C[(size_t)row * N + col] = acc[m][n][r] * scale;
      }
}

// ---------------- 256x256 deep-pipelined QKV GEMM (T3+T4 structure) ----------------
#define SHALF(Sbase, Gbase)                                                  \
  do {                                                                       \
    _Pragma("unroll") for (int j_ = 0; j_ < 2; ++j_) {                       \
      const int c_ = wid * 2 + j_;                                           \
      gload16((Gbase) + (size_t)(c_ * 8 + (lane >> 3)) * EE +                \
                  (((lane & 7) ^ (lane >> 3)) << 3),                         \
              (Sbase) + c_ * 512);                                           \
    }                                                                        \
  } while (0)

#define CHUNK(mp)                                                            \
  do {                                                                       \
    __builtin_amdgcn_s_setprio(1);                                           \
    _Pragma("unroll") for (int mm_ = 0; mm_ < 2; ++mm_) {                    \
      const int m_ = (mp) * 2 + mm_;                                         \
      _Pragma("unroll") for (int n_ = 0; n_ < 4; ++n_) {                     \
        acc[m_][n_] = __builtin_amdgcn_mfma_f32_16x16x32_bf16(               \
            af[m_][0], bfr[n_][0], acc[m_][n_], 0, 0, 0);                    \
        acc[m_][n_] = __builtin_amdgcn_mfma_f32_16x16x32_bf16(               \
            af[m_][1], bfr[n_][1], acc[m_][n_], 0, 0, 0);                    \
      }                                                                      \
    }                                                                        \
    __builtin_amdgcn_s_setprio(0);                                           \
  } while (0)

__global__ __launch_bounds__(512, 2) void qkv_gemm256(const ushort_t* __restrict__ A,
                                                      const ushort_t* __restrict__ B,
                                                      ushort_t* __restrict__ C,
                                                      float scale) {
  __shared__ ushort_t Asm[2][16384];
  __shared__ ushort_t Bsm[2][16384];
  const int NKT = EE / 64;  // 16
  const int tid = threadIdx.x, lane = tid & 63, wid = tid >> 6;
  const int wr = wid >> 2, wc = wid & 3;
  const int r16 = lane & 15, g = lane >> 4;
  const int w = (blockIdx.x & 7) * 24 + (blockIdx.x >> 3);
  const int bx = w & 15, by = w >> 4;
  const int m0 = bx * 256, n0 = by * 256;
  const ushort_t* Ab = A + (size_t)m0 * EE;
  const ushort_t* Bb = B + (size_t)n0 * EE;

#pragma unroll
  for (int kt = 0; kt < 2; ++kt) {
    SHALF(Asm[kt], Ab + kt * 64);
    SHALF(Asm[kt] + 8192, Ab + (size_t)128 * EE + kt * 64);
    SHALF(Bsm[kt], Bb + kt * 64);
    SHALF(Bsm[kt] + 8192, Bb + (size_t)128 * EE + kt * 64);
  }

  f32x4 acc[8][4] = {};
  for (int t = 0; t < NKT; ++t) {
    const int b = t & 1;
    if (t < NKT - 1) asm volatile("s_waitcnt vmcnt(8)" ::: "memory");
    else             asm volatile("s_waitcnt vmcnt(0)" ::: "memory");
    __builtin_amdgcn_s_barrier();
    asm volatile("" ::: "memory");
    bf16x8 af[8][2], bfr[4][2];
#pragma unroll
    for (int m = 0; m < 8; ++m) {
      const int row = wr * 128 + m * 16 + r16;
#pragma unroll
      for (int kk = 0; kk < 2; ++kk)
        af[m][kk] = *reinterpret_cast<const bf16x8*>(
            Asm[b] + row * 64 + (((kk * 4 + g) ^ (r16 & 7)) << 3));
    }
#pragma unroll
    for (int n = 0; n < 4; ++n) {
      const int row = wc * 64 + n * 16 + r16;
#pragma unroll
      for (int kk = 0; kk < 2; ++kk)
        bfr[n][kk] = *reinterpret_cast<const bf16x8*>(
            Bsm[b] + row * 64 + (((kk * 4 + g) ^ (r16 & 7)) << 3));
    }
    asm volatile("s_waitcnt lgkmcnt(0)" ::: "memory");
    __builtin_amdgcn_s_barrier();
    asm volatile("" ::: "memory");
    const int ts = t + 2;
    const bool st = ts < NKT;
    if (st) SHALF(Asm[b], Ab + ts * 64);
    CHUNK(0);
    if (st) SHALF(Asm[b] + 8192, Ab + (size_t)128 * EE + ts * 64);
    CHUNK(1);
    if (st) SHALF(Bsm[b], Bb + ts * 64);
    CHUNK(2);
    if (st) SHALF(Bsm[b] + 8192, Bb + (size_t)128 * EE + ts * 64);
    CHUNK(3);
  }

  const size_t MN = (size_t)4096 * EE;
#pragma unroll
  for (int m = 0; m < 8; ++m)
#pragma unroll
    for (int n = 0; n < 4; ++n) {
      const int col = n0 + wc * 64 + n * 16 + r16;
      const int seg = col >> 10;
      const int cl = col & 1023;
      if (seg == 2) {
        int row0 = m0 + wr * 128 + m * 16 + g * 4;
        int bb2 = row0 >> 11, t0v = row0 & (TT - 1);
        ushort4 pk;
        pk.x = f2bf(acc[m][n][0]); pk.y = f2bf(acc[m][n][1]);
        pk.z = f2bf(acc[m][n][2]); pk.w = f2bf(acc[m][n][3]);
        *reinterpret_cast<ushort4*>(
            C + 2 * MN + ((size_t)(bb2 * 16 + (cl >> 6)) * 64 + (cl & 63)) * TT + t0v) = pk;
      } else {
        const float sc = (seg == 0) ? scale : 1.0f;
        const size_t base = (size_t)seg * MN;
#pragma unroll
        for (int r = 0; r < 4; ++r) {
          int row = m0 + wr * 128 + m * 16 + g * 4 + r;
          C[base + (size_t)row * EE + cl] = f2bf(acc[m][n][r] * sc);
        }
      }
    }
}

// ---------------- fused dual-softmax flash attention (r11 + depth-3 counted vmcnt) ----
// 4-wave blocks (QBLK=128), KVBLK=64, TRIPLE-buffered K/V staging: at each
// barrier only the oldest tile's 4 loads are drained (vmcnt(4)); the next
// tile's loads ride across the raw s_barrier (T4). WAR on buffer (it+2)%3 is
// two barriers away; lgkm drains before MFMA use guarantee reads completed
// before barrier arrival. (row&7) 16B-XOR swizzle, pre-swizzled source.

#define PHALF(sv, lacc, oT0, oT1, vf)                                                   \
  do {                                                                                  \
    float p_[16];                                                                       \
    _Pragma("unroll") for (int i_ = 0; i_ < 16; ++i_) p_[i_] = fexp2(sv[i_]);           \
    lacc += (((p_[0] + p_[1]) + (p_[2] + p_[3])) + ((p_[4] + p_[5]) + (p_[6] + p_[7]))) \
          + (((p_[8] + p_[9]) + (p_[10] + p_[11])) +                                    \
             ((p_[12] + p_[13]) + (p_[14] + p_[15])));                                  \
    auto wA_ = __builtin_amdgcn_permlane32_swap((int)cvtpk(p_[0], p_[1]),               \
                                                (int)cvtpk(p_[4], p_[5]), false, false);\
    auto wB_ = __builtin_amdgcn_permlane32_swap((int)cvtpk(p_[2], p_[3]),               \
                                                (int)cvtpk(p_[6], p_[7]), false, false);\
    auto wC_ = __builtin_amdgcn_permlane32_swap((int)cvtpk(p_[8], p_[9]),               \
                                                (int)cvtpk(p_[12], p_[13]), false, false);\
    auto wD_ = __builtin_amdgcn_permlane32_swap((int)cvtpk(p_[10], p_[11]),             \
                                                (int)cvtpk(p_[14], p_[15]), false, false);\
    bf16x8 pa0_ = mkfrag(wA_[0], wB_[0], wA_[1], wB_[1]);                               \
    bf16x8 pa1_ = mkfrag(wC_[0], wD_[0], wC_[1], wD_[1]);                               \
    oT0 = __builtin_amdgcn_mfma_f32_32x32x16_bf16(pa0_, vf[0][0], oT0, 0, 0, 0);        \
    oT0 = __builtin_amdgcn_mfma_f32_32x32x16_bf16(pa1_, vf[1][0], oT0, 0, 0, 0);        \
    oT1 = __builtin_amdgcn_mfma_f32_32x32x16_bf16(pa0_, vf[0][1], oT1, 0, 0, 0);        \
    oT1 = __builtin_amdgcn_mfma_f32_32x32x16_bf16(pa1_, vf[1][1], oT1, 0, 0, 0);        \
  } while (0)

// Stage one 64-kv tile into explicit buffers: 4 gload16/wave (2 K + 2 V).
#define STAGE3(Kdst, Vdst, kv0)                                                         \
  do {                                                                                  \
    const int r8_ = lane >> 3;                                                          \
    const int g_ = (lane & 7) ^ r8_;                                                    \
    _Pragma("unroll") for (int c2_ = 0; c2_ < 2; ++c2_) {                               \
      const int c_ = wid * 2 + c2_;                                                     \
      gload16(Kg + (size_t)((kv0) + c_ * 8 + r8_) * EE + g_ * 8,                        \
              (Kdst) + c_ * 512);                                                       \
      gload16(Vg + (size_t)(c_ * 8 + r8_) * TT + (kv0) + g_ * 8,                        \
              (Vdst) + c_ * 512);                                                       \
    }                                                                                   \
  } while (0)

__global__ __launch_bounds__(256, 2) void attn_fused(
    const ushort_t* __restrict__ Q, const ushort_t* __restrict__ K,
    const ushort_t* __restrict__ Vt,
    const float* __restrict__ lq1, const float* __restrict__ lk1,
    const float* __restrict__ lq2, const float* __restrict__ lk2,
    const float* __restrict__ w, ushort_t* __restrict__ X2) {
  __shared__ ushort_t Ksm[3][64 * 64];
  __shared__ ushort_t Vsm[3][64 * 64];
  const int tid = threadIdx.x, lane = tid & 63, wid = tid >> 6;
  const int l31 = lane & 31, hh = lane >> 5;
  const int bid = blockIdx.x;                    // 0..511
  const int slice = (bid & 7) + 8 * (bid >> 7);  // 0..31
  const int qb = (bid >> 3) & 15;                // 0..15
  const int bb = slice >> 4, h = slice & 15;
  const int q0 = qb * 128 + wid * 32;

  float prod = (lane < 32) ? lq1[l31] * lk1[l31] : lq2[l31] * lk2[l31];
#pragma unroll
  for (int off = 1; off < 32; off <<= 1) prod += __shfl_xor(prod, off, 32);
  const float lam = __expf(__shfl(prod, 0, 64)) - __expf(__shfl(prod, 32, 64)) + LAMBDA_INIT;

  const ushort_t* Qp = Q + (size_t)(bb * TT + q0 + l31) * EE + h * 64 + hh * 8;
  const bf16x8 qf00 = *reinterpret_cast<const bf16x8*>(Qp);
  const bf16x8 qf01 = *reinterpret_cast<const bf16x8*>(Qp + 16);
  const bf16x8 qf10 = *reinterpret_cast<const bf16x8*>(Qp + 32);
  const bf16x8 qf11 = *reinterpret_cast<const bf16x8*>(Qp + 48);

  const ushort_t* Kg = K + (size_t)bb * TT * EE + h * 64;
  const ushort_t* Vg = Vt + (size_t)(bb * 16 + h) * 64 * TT;
  const int swz = (l31 & 7) << 3;

  f32x16 o00 = {}, o01 = {}, o10 = {}, o11 = {};
  float l0 = 0.f, l1 = 0.f;

  STAGE3(Ksm[0], Vsm[0], 0);
  STAGE3(Ksm[1], Vsm[1], 64);
  for (int it = 0; it < 32; ++it) {
    const ushort_t* Kt_ = Ksm[it % 3];
    const ushort_t* Vt_ = Vsm[it % 3];
    // drain only tile `it`'s 4 loads; tile it+1's ride across the barrier (T4)
    if (it < 31) asm volatile("s_waitcnt vmcnt(4)" ::: "memory");
    else         asm volatile("s_waitcnt vmcnt(0)" ::: "memory");
    __builtin_amdgcn_s_barrier();
    asm volatile("" ::: "memory");
    if (it + 2 < 32) {
      const int nb = (it + 2) % 3;
      STAGE3(Ksm[nb], Vsm[nb], (it + 2) * 64);
    }
#pragma unroll
    for (int s = 0; s < 2; ++s) {  // kv sub-tiles 0-31 / 32-63
      bf16x8 kf[2][2], vf[2][2];
#pragma unroll
      for (int hf = 0; hf < 2; ++hf)
#pragma unroll
        for (int ks = 0; ks < 2; ++ks)
          kf[hf][ks] = *reinterpret_cast<const bf16x8*>(
              Kt_ + (s * 32 + l31) * 64 + ((hf * 32 + ks * 16 + hh * 8) ^ swz));
#pragma unroll
      for (int ks = 0; ks < 2; ++ks)
#pragma unroll
        for (int dc = 0; dc < 2; ++dc)
          vf[ks][dc] = *reinterpret_cast<const bf16x8*>(
              Vt_ + (dc * 32 + l31) * 64 + ((s * 32 + ks * 16 + hh * 8) ^ swz));

      __builtin_amdgcn_s_setprio(1);
      const f32x16 zz = {};
      f32x16 s0_ = __builtin_amdgcn_mfma_f32_32x32x16_bf16(kf[0][0], qf00, zz, 0, 0, 0);
      s0_ = __builtin_amdgcn_mfma_f32_32x32x16_bf16(kf[0][1], qf01, s0_, 0, 0, 0);
      f32x16 s1_ = __builtin_amdgcn_mfma_f32_32x32x16_bf16(kf[1][0], qf10, zz, 0, 0, 0);
      s1_ = __builtin_amdgcn_mfma_f32_32x32x16_bf16(kf[1][1], qf11, s1_, 0, 0, 0);
      __builtin_amdgcn_s_setprio(0);
      PHALF(s0_, l0, o00, o01, vf);
      PHALF(s1_, l1, o10, o11, vf);
    }
  }

  // l totals: lanes l31==q (lo and hi) hold disjoint kv partial sums
  {
    auto t0 = __builtin_amdgcn_permlane32_swap(__float_as_int(l0), __float_as_int(l0),
                                               false, false);
    l0 = __int_as_float(t0[0]) + __int_as_float(t0[1]);
    auto t1 = __builtin_amdgcn_permlane32_swap(__float_as_int(l1), __float_as_int(l1),
                                               false, false);
    l1 = __int_as_float(t1[0]) + __int_as_float(t1[1]);
  }

  const float w0v = w[l31];
  const float w1v = w[32 + l31];
#pragma unroll
  for (int r = 0; r < 16; ++r) {
    const int qrel = (r & 3) + 8 * (r >> 2) + 4 * hh;
    const float il0 = 1.0f / __shfl(l0, qrel, 64);
    const float il1 = lam / __shfl(l1, qrel, 64);
    const float x0 = o00[r] * il0 - o10[r] * il1;
    const float x1 = o01[r] * il0 - o11[r] * il1;
    float ss = x0 * x0 + x1 * x1;
#pragma unroll
    for (int off = 1; off < 32; off <<= 1) ss += __shfl_xor(ss, off, 64);
    const float sc = rsqrtf(ss * (1.0f / 64.0f) + 1e-5f) * (1.0f - LAMBDA_INIT);
    const size_t ob = (size_t)(bb * TT + q0 + qrel) * EE + h * 64 + l31;
    X2[ob] = f2bf(x0 * sc * w0v);
    X2[ob + 32] = f2bf(x1 * sc * w1v);
  }
}

// ---------------- launch ----------------
extern "C" void kernel_launch(void* const* d_in, const int* in_sizes, int n_in,
                              void* d_out, int out_size, void* d_ws, size_t ws_size,
                              hipStream_t stream) {
  const float* X = (const float*)d_in[0];
  const float* Wq = (const float*)d_in[1];
  const float* Wk = (const float*)d_in[2];
  const float* Wv = (const float*)d_in[3];
  const float* Wo = (const float*)d_in[4];
  const float* lq1 = (const float*)d_in[5];
  const float* lk1 = (const float*)d_in[6];
  const float* lq2 = (const float*)d_in[7];
  const float* lk2 = (const float*)d_in[8];
  const float* slw = (const float*)d_in[9];

  const int M = 4096, E = EE;

  ushort_t* Xb = (ushort_t*)d_ws;            // M*E bf16
  ushort_t* Wqb = Xb + (size_t)M * E;        // E*E  (Wq,Wk,Wv,Wo contiguous)
  ushort_t* Wob = Wqb + (size_t)3 * E * E;
  ushort_t* Qb = Wob + (size_t)E * E;        // M*E  (Qb,Kb,Vtb contiguous)
  ushort_t* Kb = Qb + (size_t)M * E;
  ushort_t* Vtb = Kb + (size_t)M * E;
  ushort_t* X2 = Vtb + (size_t)M * E;

  cvt_all<<<8192, 256, 0, stream>>>(X, Wq, Wk, Wv, Wo, Xb);

  // fused QKV projection, 256^2 deep-pipelined. Q prescaled by hd^-0.5 * log2e.
  qkv_gemm256<<<192, 512, 0, stream>>>(Xb, Wqb, Qb,
                                       0.17677669529663687f * 1.4426950408889634f);

  attn_fused<<<512, 256, 0, stream>>>(Qb, Kb, Vtb, lq1, lk1, lq2, lk2, slw, X2);

  gemm_bt<<<dim3(M / 128, E / 128), 256, 0, stream>>>(X2, Wob, (float*)d_out, M, E, E,
                                                      1.0f);
}

// Round 14
// 131.614 us; speedup vs baseline: 1.1449x; 1.0392x over previous
//
#include <hip/hip_runtime.h>

typedef short bf16x8 __attribute__((ext_vector_type(8)));
typedef float f32x4 __attribute__((ext_vector_type(4)));
typedef float f32x16 __attribute__((ext_vector_type(16)));
typedef unsigned short ushort_t;
typedef unsigned int uint32;

#define LAMBDA_INIT 0.7836057665316245f
#define TT 2048
#define EE 1024

__device__ __forceinline__ ushort_t f2bf(float x) {
  uint32 b = __float_as_uint(x);
  b += 0x7fffu + ((b >> 16) & 1u);   // round-to-nearest-even
  return (ushort_t)(b >> 16);
}

__device__ __forceinline__ uint32 cvtpk(float lo, float hi) {
  uint32 r;
  asm("v_cvt_pk_bf16_f32 %0, %1, %2" : "=v"(r) : "v"(lo), "v"(hi));
  return r;
}

// raw v_exp_f32 via hazard-safe builtin (args bounded; libm guard unnecessary)
__device__ __forceinline__ float fexp2(float x) {
#if __has_builtin(__builtin_amdgcn_exp2f)
  return __builtin_amdgcn_exp2f(x);
#else
  return exp2f(x);
#endif
}

__device__ __forceinline__ bf16x8 mkfrag(uint32 a, uint32 b, uint32 c, uint32 d) {
  union { uint32 w[4]; bf16x8 v; } u;
  u.w[0] = a; u.w[1] = b; u.w[2] = c; u.w[3] = d;
  return u.v;
}

__device__ __forceinline__ void gload16(const void* g, void* l) {
  __builtin_amdgcn_global_load_lds(
      (const __attribute__((address_space(1))) uint32*)g,
      (__attribute__((address_space(3))) uint32*)l, 16, 0, 0);
}

// ------------- fused fp32 -> bf16 conversion: X,Wq,Wk,Wv,Wo -> contiguous ws -------------
__global__ __launch_bounds__(256) void cvt_all(const float* __restrict__ X,
                                               const float* __restrict__ Wq,
                                               const float* __restrict__ Wk,
                                               const float* __restrict__ Wv,
                                               const float* __restrict__ Wo,
                                               ushort_t* __restrict__ out) {
  const int i = blockIdx.x * 256 + threadIdx.x;  // float4 index, 2097152 total
  const float* src;
  int off;
  if (i < 1048576)      { src = X;  off = 0; }
  else if (i < 1310720) { src = Wq; off = 1048576; }
  else if (i < 1572864) { src = Wk; off = 1310720; }
  else if (i < 1835008) { src = Wv; off = 1572864; }
  else                  { src = Wo; off = 1835008; }
  const float4 v = reinterpret_cast<const float4*>(src)[i - off];
  ushort4 o;
  o.x = f2bf(v.x); o.y = f2bf(v.y); o.z = f2bf(v.z); o.w = f2bf(v.w);
  reinterpret_cast<ushort4*>(out)[i] = o;
}

// ---------------- out-projection GEMM, deep-pipelined 128x128/BK64 ----------------
// C fp32 [4096,1024] = A[4096,1024] @ Wo[1024,1024]^T. 4 waves (2x2), dbuf
// 32KB LDS pair (64KB -> 2 blocks/CU), counted vmcnt(8) + raw s_barrier
// (tile t+1's loads ride across), (row&7) 16B-XOR swizzle, stages interleaved
// with MFMA chunks. Direct specialization of the verified qkv_gemm256 structure.
#define OSHALF(Sbase, Gbase)                                                 \
  do {                                                                       \
    _Pragma("unroll") for (int j_ = 0; j_ < 4; ++j_) {                       \
      const int c_ = wid * 4 + j_;                                           \
      gload16((Gbase) + (size_t)(c_ * 8 + (lane >> 3)) * EE +                \
                  (((lane & 7) ^ (lane >> 3)) << 3),                         \
              (Sbase) + c_ * 512);                                           \
    }                                                                        \
  } while (0)

#define OCHUNK(mp)                                                           \
  do {                                                                       \
    __builtin_amdgcn_s_setprio(1);                                           \
    _Pragma("unroll") for (int n_ = 0; n_ < 4; ++n_) {                       \
      acc[mp][n_] = __builtin_amdgcn_mfma_f32_16x16x32_bf16(                 \
          af[mp][0], bfg[n_][0], acc[mp][n_], 0, 0, 0);                      \
      acc[mp][n_] = __builtin_amdgcn_mfma_f32_16x16x32_bf16(                 \
          af[mp][1], bfg[n_][1], acc[mp][n_], 0, 0, 0);                      \
    }                                                                        \
    __builtin_amdgcn_s_setprio(0);                                           \
  } while (0)

__global__ __launch_bounds__(256, 2) void outp_gemm(const ushort_t* __restrict__ A,
                                                    const ushort_t* __restrict__ B,
                                                    float* __restrict__ C) {
  __shared__ ushort_t Asm[2][8192];
  __shared__ ushort_t Bsm[2][8192];
  const int NKT = EE / 64;  // 16
  const int tid = threadIdx.x, lane = tid & 63, wid = tid >> 6;
  const int wr = wid >> 1, wc = wid & 1;
  const int r16 = lane & 15, g = lane >> 4;
  // XCD swizzle over 256 blocks (32/XCD); within an XCD, m varies fastest ->
  // consecutive blocks share the same 128-col Wo panel (L2-resident).
  const int w = (blockIdx.x & 7) * 32 + (blockIdx.x >> 3);
  const int bx = w & 31, by = w >> 5;  // M/128=32, N/128=8
  const int m0 = bx * 128, n0 = by * 128;
  const ushort_t* Ab = A + (size_t)m0 * EE;
  const ushort_t* Bb = B + (size_t)n0 * EE;

  // prologue: stage kt0, kt1
#pragma unroll
  for (int kt = 0; kt < 2; ++kt) {
    OSHALF(Asm[kt], Ab + kt * 64);
    OSHALF(Bsm[kt], Bb + kt * 64);
  }

  f32x4 acc[4][4] = {};
  for (int t = 0; t < NKT; ++t) {
    const int b = t & 1;
    if (t < NKT - 1) asm volatile("s_waitcnt vmcnt(8)" ::: "memory");
    else             asm volatile("s_waitcnt vmcnt(0)" ::: "memory");
    __builtin_amdgcn_s_barrier();          // tile t resident (all waves)
    asm volatile("" ::: "memory");
    bf16x8 af[4][2], bfg[4][2];
#pragma unroll
    for (int m = 0; m < 4; ++m) {
      const int row = wr * 64 + m * 16 + r16;
#pragma unroll
      for (int kk = 0; kk < 2; ++kk)
        af[m][kk] = *reinterpret_cast<const bf16x8*>(
            Asm[b] + row * 64 + (((kk * 4 + g) ^ (r16 & 7)) << 3));
    }
#pragma unroll
    for (int n = 0; n < 4; ++n) {
      const int row = wc * 64 + n * 16 + r16;
#pragma unroll
      for (int kk = 0; kk < 2; ++kk)
        bfg[n][kk] = *reinterpret_cast<const bf16x8*>(
            Bsm[b] + row * 64 + (((kk * 4 + g) ^ (r16 & 7)) << 3));
    }
    asm volatile("s_waitcnt lgkmcnt(0)" ::: "memory");
    __builtin_amdgcn_s_barrier();          // all reads done -> stages may land
    asm volatile("" ::: "memory");
    const int ts = t + 2;
    const bool st = ts < NKT;
    if (st) OSHALF(Asm[b], Ab + ts * 64);
    OCHUNK(0);
    OCHUNK(1);
    if (st) OSHALF(Bsm[b], Bb + ts * 64);
    OCHUNK(2);
    OCHUNK(3);
  }

#pragma unroll
  for (int m = 0; m < 4; ++m)
#pragma unroll
    for (int n = 0; n < 4; ++n)
#pragma unroll
      for (int r = 0; r < 4; ++r) {
        const int row = m0 + wr * 64 + m * 16 + g * 4 + r;
        const int col = n0 + wc * 64 + n * 16 + r16;
        C[(size_t)row * EE + col] = acc[m][n][r];
      }
}

// ---------------- 256x256 deep-pipelined QKV GEMM (T3+T4 structure) ----------------
#define SHALF(Sbase, Gbase)                                                  \
  do {                                                                       \
    _Pragma("unroll") for (int j_ = 0; j_ < 2; ++j_) {                       \
      const int c_ = wid * 2 + j_;                                           \
      gload16((Gbase) + (size_t)(c_ * 8 + (lane >> 3)) * EE +                \
                  (((lane & 7) ^ (lane >> 3)) << 3),                         \
              (Sbase) + c_ * 512);                                           \
    }                                                                        \
  } while (0)

#define CHUNK(mp)                                                            \
  do {                                                                       \
    __builtin_amdgcn_s_setprio(1);                                           \
    _Pragma("unroll") for (int mm_ = 0; mm_ < 2; ++mm_) {                    \
      const int m_ = (mp) * 2 + mm_;                                         \
      _Pragma("unroll") for (int n_ = 0; n_ < 4; ++n_) {                     \
        acc[m_][n_] = __builtin_amdgcn_mfma_f32_16x16x32_bf16(               \
            af[m_][0], bfr[n_][0], acc[m_][n_], 0, 0, 0);                    \
        acc[m_][n_] = __builtin_amdgcn_mfma_f32_16x16x32_bf16(               \
            af[m_][1], bfr[n_][1], acc[m_][n_], 0, 0, 0);                    \
      }                                                                      \
    }                                                                        \
    __builtin_amdgcn_s_setprio(0);                                           \
  } while (0)

__global__ __launch_bounds__(512, 2) void qkv_gemm256(const ushort_t* __restrict__ A,
                                                      const ushort_t* __restrict__ B,
                                                      ushort_t* __restrict__ C,
                                                      float scale) {
  __shared__ ushort_t Asm[2][16384];
  __shared__ ushort_t Bsm[2][16384];
  const int NKT = EE / 64;  // 16
  const int tid = threadIdx.x, lane = tid & 63, wid = tid >> 6;
  const int wr = wid >> 2, wc = wid & 3;
  const int r16 = lane & 15, g = lane >> 4;
  const int w = (blockIdx.x & 7) * 24 + (blockIdx.x >> 3);
  const int bx = w & 15, by = w >> 4;
  const int m0 = bx * 256, n0 = by * 256;
  const ushort_t* Ab = A + (size_t)m0 * EE;
  const ushort_t* Bb = B + (size_t)n0 * EE;

#pragma unroll
  for (int kt = 0; kt < 2; ++kt) {
    SHALF(Asm[kt], Ab + kt * 64);
    SHALF(Asm[kt] + 8192, Ab + (size_t)128 * EE + kt * 64);
    SHALF(Bsm[kt], Bb + kt * 64);
    SHALF(Bsm[kt] + 8192, Bb + (size_t)128 * EE + kt * 64);
  }

  f32x4 acc[8][4] = {};
  for (int t = 0; t < NKT; ++t) {
    const int b = t & 1;
    if (t < NKT - 1) asm volatile("s_waitcnt vmcnt(8)" ::: "memory");
    else             asm volatile("s_waitcnt vmcnt(0)" ::: "memory");
    __builtin_amdgcn_s_barrier();
    asm volatile("" ::: "memory");
    bf16x8 af[8][2], bfr[4][2];
#pragma unroll
    for (int m = 0; m < 8; ++m) {
      const int row = wr * 128 + m * 16 + r16;
#pragma unroll
      for (int kk = 0; kk < 2; ++kk)
        af[m][kk] = *reinterpret_cast<const bf16x8*>(
            Asm[b] + row * 64 + (((kk * 4 + g) ^ (r16 & 7)) << 3));
    }
#pragma unroll
    for (int n = 0; n < 4; ++n) {
      const int row = wc * 64 + n * 16 + r16;
#pragma unroll
      for (int kk = 0; kk < 2; ++kk)
        bfr[n][kk] = *reinterpret_cast<const bf16x8*>(
            Bsm[b] + row * 64 + (((kk * 4 + g) ^ (r16 & 7)) << 3));
    }
    asm volatile("s_waitcnt lgkmcnt(0)" ::: "memory");
    __builtin_amdgcn_s_barrier();
    asm volatile("" ::: "memory");
    const int ts = t + 2;
    const bool st = ts < NKT;
    if (st) SHALF(Asm[b], Ab + ts * 64);
    CHUNK(0);
    if (st) SHALF(Asm[b] + 8192, Ab + (size_t)128 * EE + ts * 64);
    CHUNK(1);
    if (st) SHALF(Bsm[b], Bb + ts * 64);
    CHUNK(2);
    if (st) SHALF(Bsm[b] + 8192, Bb + (size_t)128 * EE + ts * 64);
    CHUNK(3);
  }

  const size_t MN = (size_t)4096 * EE;
#pragma unroll
  for (int m = 0; m < 8; ++m)
#pragma unroll
    for (int n = 0; n < 4; ++n) {
      const int col = n0 + wc * 64 + n * 16 + r16;
      const int seg = col >> 10;
      const int cl = col & 1023;
      if (seg == 2) {
        int row0 = m0 + wr * 128 + m * 16 + g * 4;
        int bb2 = row0 >> 11, t0v = row0 & (TT - 1);
        ushort4 pk;
        pk.x = f2bf(acc[m][n][0]); pk.y = f2bf(acc[m][n][1]);
        pk.z = f2bf(acc[m][n][2]); pk.w = f2bf(acc[m][n][3]);
        *reinterpret_cast<ushort4*>(
            C + 2 * MN + ((size_t)(bb2 * 16 + (cl >> 6)) * 64 + (cl & 63)) * TT + t0v) = pk;
      } else {
        const float sc = (seg == 0) ? scale : 1.0f;
        const size_t base = (size_t)seg * MN;
#pragma unroll
        for (int r = 0; r < 4; ++r) {
          int row = m0 + wr * 128 + m * 16 + g * 4 + r;
          C[base + (size_t)row * EE + cl] = f2bf(acc[m][n][r] * sc);
        }
      }
    }
}

// ---------------- fused dual-softmax flash attention (r13: depth-3 counted vmcnt) ----
#define PHALF(sv, lacc, oT0, oT1, vf)                                                   \
  do {                                                                                  \
    float p_[16];                                                                       \
    _Pragma("unroll") for (int i_ = 0; i_ < 16; ++i_) p_[i_] = fexp2(sv[i_]);           \
    lacc += (((p_[0] + p_[1]) + (p_[2] + p_[3])) + ((p_[4] + p_[5]) + (p_[6] + p_[7]))) \
          + (((p_[8] + p_[9]) + (p_[10] + p_[11])) +                                    \
             ((p_[12] + p_[13]) + (p_[14] + p_[15])));                                  \
    auto wA_ = __builtin_amdgcn_permlane32_swap((int)cvtpk(p_[0], p_[1]),               \
                                                (int)cvtpk(p_[4], p_[5]), false, false);\
    auto wB_ = __builtin_amdgcn_permlane32_swap((int)cvtpk(p_[2], p_[3]),               \
                                                (int)cvtpk(p_[6], p_[7]), false, false);\
    auto wC_ = __builtin_amdgcn_permlane32_swap((int)cvtpk(p_[8], p_[9]),               \
                                                (int)cvtpk(p_[12], p_[13]), false, false);\
    auto wD_ = __builtin_amdgcn_permlane32_swap((int)cvtpk(p_[10], p_[11]),             \
                                                (int)cvtpk(p_[14], p_[15]), false, false);\
    bf16x8 pa0_ = mkfrag(wA_[0], wB_[0], wA_[1], wB_[1]);                               \
    bf16x8 pa1_ = mkfrag(wC_[0], wD_[0], wC_[1], wD_[1]);                               \
    oT0 = __builtin_amdgcn_mfma_f32_32x32x16_bf16(pa0_, vf[0][0], oT0, 0, 0, 0);        \
    oT0 = __builtin_amdgcn_mfma_f32_32x32x16_bf16(pa1_, vf[1][0], oT0, 0, 0, 0);        \
    oT1 = __builtin_amdgcn_mfma_f32_32x32x16_bf16(pa0_, vf[0][1], oT1, 0, 0, 0);        \
    oT1 = __builtin_amdgcn_mfma_f32_32x32x16_bf16(pa1_, vf[1][1], oT1, 0, 0, 0);        \
  } while (0)

#define STAGE3(Kdst, Vdst, kv0)                                                         \
  do {                                                                                  \
    const int r8_ = lane >> 3;                                                          \
    const int g_ = (lane & 7) ^ r8_;                                                    \
    _Pragma("unroll") for (int c2_ = 0; c2_ < 2; ++c2_) {                               \
      const int c_ = wid * 2 + c2_;                                                     \
      gload16(Kg + (size_t)((kv0) + c_ * 8 + r8_) * EE + g_ * 8,                        \
              (Kdst) + c_ * 512);                                                       \
      gload16(Vg + (size_t)(c_ * 8 + r8_) * TT + (kv0) + g_ * 8,                        \
              (Vdst) + c_ * 512);                                                       \
    }                                                                                   \
  } while (0)

__global__ __launch_bounds__(256, 2) void attn_fused(
    const ushort_t* __restrict__ Q, const ushort_t* __restrict__ K,
    const ushort_t* __restrict__ Vt,
    const float* __restrict__ lq1, const float* __restrict__ lk1,
    const float* __restrict__ lq2, const float* __restrict__ lk2,
    const float* __restrict__ w, ushort_t* __restrict__ X2) {
  __shared__ ushort_t Ksm[3][64 * 64];
  __shared__ ushort_t Vsm[3][64 * 64];
  const int tid = threadIdx.x, lane = tid & 63, wid = tid >> 6;
  const int l31 = lane & 31, hh = lane >> 5;
  const int bid = blockIdx.x;                    // 0..511
  const int slice = (bid & 7) + 8 * (bid >> 7);  // 0..31
  const int qb = (bid >> 3) & 15;                // 0..15
  const int bb = slice >> 4, h = slice & 15;
  const int q0 = qb * 128 + wid * 32;

  float prod = (lane < 32) ? lq1[l31] * lk1[l31] : lq2[l31] * lk2[l31];
#pragma unroll
  for (int off = 1; off < 32; off <<= 1) prod += __shfl_xor(prod, off, 32);
  const float lam = __expf(__shfl(prod, 0, 64)) - __expf(__shfl(prod, 32, 64)) + LAMBDA_INIT;

  const ushort_t* Qp = Q + (size_t)(bb * TT + q0 + l31) * EE + h * 64 + hh * 8;
  const bf16x8 qf00 = *reinterpret_cast<const bf16x8*>(Qp);
  const bf16x8 qf01 = *reinterpret_cast<const bf16x8*>(Qp + 16);
  const bf16x8 qf10 = *reinterpret_cast<const bf16x8*>(Qp + 32);
  const bf16x8 qf11 = *reinterpret_cast<const bf16x8*>(Qp + 48);

  const ushort_t* Kg = K + (size_t)bb * TT * EE + h * 64;
  const ushort_t* Vg = Vt + (size_t)(bb * 16 + h) * 64 * TT;
  const int swz = (l31 & 7) << 3;

  f32x16 o00 = {}, o01 = {}, o10 = {}, o11 = {};
  float l0 = 0.f, l1 = 0.f;

  STAGE3(Ksm[0], Vsm[0], 0);
  STAGE3(Ksm[1], Vsm[1], 64);
  for (int it = 0; it < 32; ++it) {
    const ushort_t* Kt_ = Ksm[it % 3];
    const ushort_t* Vt_ = Vsm[it % 3];
    if (it < 31) asm volatile("s_waitcnt vmcnt(4)" ::: "memory");
    else         asm volatile("s_waitcnt vmcnt(0)" ::: "memory");
    __builtin_amdgcn_s_barrier();
    asm volatile("" ::: "memory");
    if (it + 2 < 32) {
      const int nb = (it + 2) % 3;
      STAGE3(Ksm[nb], Vsm[nb], (it + 2) * 64);
    }
#pragma unroll
    for (int s = 0; s < 2; ++s) {
      bf16x8 kf[2][2], vf[2][2];
#pragma unroll
      for (int hf = 0; hf < 2; ++hf)
#pragma unroll
        for (int ks = 0; ks < 2; ++ks)
          kf[hf][ks] = *reinterpret_cast<const bf16x8*>(
              Kt_ + (s * 32 + l31) * 64 + ((hf * 32 + ks * 16 + hh * 8) ^ swz));
#pragma unroll
      for (int ks = 0; ks < 2; ++ks)
#pragma unroll
        for (int dc = 0; dc < 2; ++dc)
          vf[ks][dc] = *reinterpret_cast<const bf16x8*>(
              Vt_ + (dc * 32 + l31) * 64 + ((s * 32 + ks * 16 + hh * 8) ^ swz));

      __builtin_amdgcn_s_setprio(1);
      const f32x16 zz = {};
      f32x16 s0_ = __builtin_amdgcn_mfma_f32_32x32x16_bf16(kf[0][0], qf00, zz, 0, 0, 0);
      s0_ = __builtin_amdgcn_mfma_f32_32x32x16_bf16(kf[0][1], qf01, s0_, 0, 0, 0);
      f32x16 s1_ = __builtin_amdgcn_mfma_f32_32x32x16_bf16(kf[1][0], qf10, zz, 0, 0, 0);
      s1_ = __builtin_amdgcn_mfma_f32_32x32x16_bf16(kf[1][1], qf11, s1_, 0, 0, 0);
      __builtin_amdgcn_s_setprio(0);
      PHALF(s0_, l0, o00, o01, vf);
      PHALF(s1_, l1, o10, o11, vf);
    }
  }

  {
    auto t0 = __builtin_amdgcn_permlane32_swap(__float_as_int(l0), __float_as_int(l0),
                                               false, false);
    l0 = __int_as_float(t0[0]) + __int_as_float(t0[1]);
    auto t1 = __builtin_amdgcn_permlane32_swap(__float_as_int(l1), __float_as_int(l1),
                                               false, false);
    l1 = __int_as_float(t1[0]) + __int_as_float(t1[1]);
  }

  const float w0v = w[l31];
  const float w1v = w[32 + l31];
#pragma unroll
  for (int r = 0; r < 16; ++r) {
    const int qrel = (r & 3) + 8 * (r >> 2) + 4 * hh;
    const float il0 = 1.0f / __shfl(l0, qrel, 64);
    const float il1 = lam / __shfl(l1, qrel, 64);
    const float x0 = o00[r] * il0 - o10[r] * il1;
    const float x1 = o01[r] * il0 - o11[r] * il1;
    float ss = x0 * x0 + x1 * x1;
#pragma unroll
    for (int off = 1; off < 32; off <<= 1) ss += __shfl_xor(ss, off, 64);
    const float sc = rsqrtf(ss * (1.0f / 64.0f) + 1e-5f) * (1.0f - LAMBDA_INIT);
    const size_t ob = (size_t)(bb * TT + q0 + qrel) * EE + h * 64 + l31;
    X2[ob] = f2bf(x0 * sc * w0v);
    X2[ob + 32] = f2bf(x1 * sc * w1v);
  }
}

// ---------------- launch ----------------
extern "C" void kernel_launch(void* const* d_in, const int* in_sizes, int n_in,
                              void* d_out, int out_size, void* d_ws, size_t ws_size,
                              hipStream_t stream) {
  const float* X = (const float*)d_in[0];
  const float* Wq = (const float*)d_in[1];
  const float* Wk = (const float*)d_in[2];
  const float* Wv = (const float*)d_in[3];
  const float* Wo = (const float*)d_in[4];
  const float* lq1 = (const float*)d_in[5];
  const float* lk1 = (const float*)d_in[6];
  const float* lq2 = (const float*)d_in[7];
  const float* lk2 = (const float*)d_in[8];
  const float* slw = (const float*)d_in[9];

  const int M = 4096, E = EE;

  ushort_t* Xb = (ushort_t*)d_ws;            // M*E bf16
  ushort_t* Wqb = Xb + (size_t)M * E;        // E*E  (Wq,Wk,Wv,Wo contiguous)
  ushort_t* Wob = Wqb + (size_t)3 * E * E;
  ushort_t* Qb = Wob + (size_t)E * E;        // M*E  (Qb,Kb,Vtb contiguous)
  ushort_t* Kb = Qb + (size_t)M * E;
  ushort_t* Vtb = Kb + (size_t)M * E;
  ushort_t* X2 = Vtb + (size_t)M * E;

  cvt_all<<<8192, 256, 0, stream>>>(X, Wq, Wk, Wv, Wo, Xb);

  // fused QKV projection, 256^2 deep-pipelined. Q prescaled by hd^-0.5 * log2e.
  qkv_gemm256<<<192, 512, 0, stream>>>(Xb, Wqb, Qb,
                                       0.17677669529663687f * 1.4426950408889634f);

  attn_fused<<<512, 256, 0, stream>>>(Qb, Kb, Vtb, lq1, lk1, lq2, lk2, slw, X2);

  outp_gemm<<<256, 256, 0, stream>>>(X2, Wob, (float*)d_out);
}